// Round 7
// baseline (1031.142 us; speedup 1.0000x reference)
//
#include <hip/hip_runtime.h>

typedef _Float16 f16x8 __attribute__((ext_vector_type(8)));
typedef float f32x4 __attribute__((ext_vector_type(4)));
typedef unsigned int u32;

#define EPS 1e-5f

__device__ __forceinline__ short f2h(float x) {
    _Float16 h = (_Float16)x;   // RNE v_cvt_f16_f32
    union { _Float16 h; short s; } u;
    u.h = h;
    return u.s;
}

// async global->LDS DMA, 16 B per lane. LDS dest = wave-uniform base + lane*16.
__device__ __forceinline__ void gl_lds16(const void* g, void* l) {
    __builtin_amdgcn_global_load_lds(
        (const __attribute__((address_space(1))) u32*)g,
        (__attribute__((address_space(3))) u32*)l, 16, 0, 0);
}

// ---------------------------------------------------------------------------
// prep: WtM[l][f][k] fp16 <- Wm[l][k][f] (16-B output chunks); WtF[f][k] fp16
// (f padded to 48); stats zeroed.
// ---------------------------------------------------------------------------
__global__ __launch_bounds__(256) void prep_kernel(
        const float* __restrict__ Wm, const float* __restrict__ Wl,
        short* __restrict__ WtM, short* __restrict__ WtF,
        float* __restrict__ stats) {
    const long T1c = 14L * 896 * 128 / 8;   // 200704 16-B chunks
    const long T2 = 48L * 896;
    const long T3 = 15L * 256;
    long i = (long)blockIdx.x * blockDim.x + threadIdx.x;
    if (i < T1c) {
        long c8 = i * 8;
        long l = c8 / 114688;
        long r = c8 % 114688;
        long f = r / 896;
        long k = r % 896;
        const float* src = Wm + l * 114688 + f;
        union { f16x8 h; short s[8]; } o;
#pragma unroll
        for (int e = 0; e < 8; ++e) o.s[e] = f2h(src[(k + e) * 128]);
        *(f16x8*)&WtM[c8] = o.h;
    } else if (i < T1c + T2) {
        long j = i - T1c;
        long f = j / 896;
        long k = j % 896;
        WtF[j] = (f < 36) ? f2h(Wl[k * 36 + f]) : (short)0;
    } else if (i < T1c + T2 + T3) {
        stats[i - T1c - T2] = 0.0f;
    }
}

// ---------------------------------------------------------------------------
// gx: GX[n*21 + e] = x[idx[n*7 + e/3]*3 + e%3]. Thread-per-element, pure TLP.
// ---------------------------------------------------------------------------
__global__ __launch_bounds__(256) void gx_kernel(
        const float* __restrict__ x, const int* __restrict__ idx,
        float* __restrict__ GX, int total) {
    for (int t = blockIdx.x * blockDim.x + threadIdx.x; t < total;
         t += gridDim.x * blockDim.x) {
        int n = t / 21;
        int e = t - n * 21;
        int j = e / 3;
        int c = e - j * 3;
        int r = idx[n * 7 + j];
        GX[t] = x[(long)r * 3 + c];
    }
}

// ---------------------------------------------------------------------------
// l0: dense h16[n,f] = b0[f] + GX[n,:21] @ W0[:,f]; fp16 store + fp32 stats.
// Block 256 = 2 nodes x 128 feats per iteration; W0 in LDS; GX row loads are
// lane-uniform (broadcast).
// ---------------------------------------------------------------------------
__global__ __launch_bounds__(256) void l0_kernel(
        const float* __restrict__ GX, const float* __restrict__ W0,
        const float* __restrict__ b0, unsigned short* __restrict__ h16,
        float* __restrict__ stats, int N) {
    __shared__ float sW[21 * 128];
    __shared__ float sstat[256];
    const int tid = threadIdx.x;
    for (int i = tid; i < 21 * 128; i += 256) sW[i] = W0[i];
    sstat[tid] = 0.f;
    __syncthreads();

    const int f = tid & 127;
    const int half = tid >> 7;
    const float bb = b0[f];
    float s = 0.f, ss = 0.f;
    for (int n = blockIdx.x * 2 + half; n < N; n += gridDim.x * 2) {
        const float* gx = GX + (long)n * 21;
        float acc = bb;
#pragma unroll
        for (int k = 0; k < 21; ++k) acc = fmaf(gx[k], sW[k * 128 + f], acc);
        h16[(long)n * 128 + f] = (unsigned short)f2h(acc);
        s += acc;
        ss += acc * acc;
    }
    atomicAdd(&sstat[f], s);
    atomicAdd(&sstat[128 + f], ss);
    __syncthreads();
    if (tid < 256) atomicAdd(&stats[tid], sstat[tid]);
}

// ---------------------------------------------------------------------------
// bn_gather: G[m, j*128+f] = relu(sc[f]*h16[idx[m*7+j]*128+f] + sh[f]).
// Thread per 16-B chunk; coalesced writes; gather latency hidden by TLP.
// ---------------------------------------------------------------------------
__global__ __launch_bounds__(256) void bn_gather_kernel(
        const unsigned short* __restrict__ h16, const float* __restrict__ stats,
        const float* __restrict__ g, const float* __restrict__ be,
        const int* __restrict__ idx, unsigned short* __restrict__ G,
        int total, float invN) {
    __shared__ float sSc[128], sSh[128];
    const int tid = threadIdx.x;
    if (tid < 128) {
        float mu = stats[tid] * invN;
        float var = stats[128 + tid] * invN - mu * mu;
        float rs = rsqrtf(var + EPS);
        float sc = g[tid] * rs;
        sSc[tid] = sc;
        sSh[tid] = be[tid] - mu * sc;
    }
    __syncthreads();
    for (int t = blockIdx.x * blockDim.x + tid; t < total; t += gridDim.x * blockDim.x) {
        int m = t / 112;
        int rem = t - m * 112;
        int j = rem >> 4;
        int c = rem & 15;
        int row = idx[m * 7 + j];
        f16x8 v = *(const f16x8*)&h16[(long)row * 128 + c * 8];
        union { f16x8 h; unsigned short us[8]; } o;
#pragma unroll
        for (int e = 0; e < 8; ++e) {
            int f = c * 8 + e;
            float y = fmaxf(fmaf((float)v[e], sSc[f], sSh[f]), 0.f);
            o.us[e] = (unsigned short)f2h(y);
        }
        *(f16x8*)&G[(long)t * 8] = o.h;
    }
}

// ---------------------------------------------------------------------------
// gemm_g v2: dense [N,896]@[896,128], DOUBLE-BUFFERED global_load_lds slabs.
// Block 256 = 4 waves (2x2), tile 128x128, BK=64, 14 slabs; slab k+1's DMA is
// issued before computing slab k (one barrier per slab, drain overlapped).
// XOR chunk swizzle (slot = chunk ^ (row&7)) -> conflict-free ds_read_b128.
// ---------------------------------------------------------------------------
__global__ __launch_bounds__(256, 2) void gemm_g_kernel(
        const unsigned short* __restrict__ G, const short* __restrict__ Wt,
        const float* __restrict__ bvec, unsigned short* __restrict__ h16,
        float* __restrict__ stats, int N) {
    __shared__ short sA[2][128 * 64];   // 2 x 16 KB
    __shared__ short sB[2][128 * 64];

    const int tid = threadIdx.x;
    const int wave = tid >> 6;
    const int lane = tid & 63;
    const int quad = lane >> 4;
    const int l16 = lane & 15;
    const int wm = wave & 1;
    const int wf = wave >> 1;
    const int m0 = blockIdx.x * 128;

    const int srow = lane >> 3;             // row within 8-row DMA group
    const int schunk = (lane & 7) ^ srow;   // global 16-B chunk to fetch

    long arow[4], brow[4];
#pragma unroll
    for (int d = 0; d < 4; ++d) {
        int r = m0 + wave * 32 + d * 8 + srow;
        r = (r < N) ? r : (N - 1);
        arow[d] = (long)r * 896;
        brow[d] = (long)(wave * 32 + d * 8 + srow) * 896;
    }

    // stage slab ks into buffer p (8 DMA instructions per thread)
    auto stage = [&](int ks, int p) {
        const int kb = ks * 64 + schunk * 8;
#pragma unroll
        for (int d = 0; d < 4; ++d)
            gl_lds16(G + arow[d] + kb, &sA[p][(wave * 32 + d * 8) * 64]);
#pragma unroll
        for (int d = 0; d < 4; ++d)
            gl_lds16(Wt + brow[d] + kb, &sB[p][(wave * 32 + d * 8) * 64]);
    };

    stage(0, 0);   // prologue prefetch

    f32x4 acc[4][4];
#pragma unroll
    for (int ni = 0; ni < 4; ++ni) {
        float bv = bvec[wf * 64 + ni * 16 + l16];
#pragma unroll
        for (int mi = 0; mi < 4; ++mi) {
            acc[mi][ni][0] = bv; acc[mi][ni][1] = bv;
            acc[mi][ni][2] = bv; acc[mi][ni][3] = bv;
        }
    }

#pragma unroll 1
    for (int ks = 0; ks < 14; ++ks) {
        const int p = ks & 1;
        __builtin_amdgcn_s_waitcnt(0);   // own slab-ks DMAs done
        __syncthreads();                  // => slab ks fully staged by all waves
        if (ks < 13) stage(ks + 1, p ^ 1);   // overlap with compute below

#pragma unroll
        for (int s = 0; s < 2; ++s) {
            f16x8 a[4], b[4];
#pragma unroll
            for (int mi = 0; mi < 4; ++mi) {
                int r = wm * 64 + mi * 16 + l16;
                int c = s * 4 + quad;
                a[mi] = *(const f16x8*)&sA[p][r * 64 + ((c ^ (r & 7)) * 8)];
            }
#pragma unroll
            for (int ni = 0; ni < 4; ++ni) {
                int f = wf * 64 + ni * 16 + l16;
                int c = s * 4 + quad;
                b[ni] = *(const f16x8*)&sB[p][f * 64 + ((c ^ (f & 7)) * 8)];
            }
#pragma unroll
            for (int mi = 0; mi < 4; ++mi)
#pragma unroll
                for (int ni = 0; ni < 4; ++ni)
                    acc[mi][ni] = __builtin_amdgcn_mfma_f32_16x16x32_f16(
                        a[mi], b[ni], acc[mi][ni], 0, 0, 0);
        }
    }

    // epilogue: fp16 store + stats
#pragma unroll
    for (int ni = 0; ni < 4; ++ni) {
        int feat = wf * 64 + ni * 16 + l16;
        float s = 0.f, ss = 0.f;
#pragma unroll
        for (int mi = 0; mi < 4; ++mi) {
#pragma unroll
            for (int r = 0; r < 4; ++r) {
                int node = m0 + wm * 64 + mi * 16 + quad * 4 + r;
                float v = acc[mi][ni][r];
                if (node < N) {
                    h16[(long)node * 128 + feat] = (unsigned short)f2h(v);
                    s += v;
                    ss += v * v;
                }
            }
        }
        s += __shfl_xor(s, 16);
        s += __shfl_xor(s, 32);
        ss += __shfl_xor(ss, 16);
        ss += __shfl_xor(ss, 32);
        if (quad == 0) {
            atomicAdd(&stats[feat], s);
            atomicAdd(&stats[128 + feat], ss);
        }
    }
}

// ---------------------------------------------------------------------------
// gemm_final: out[N,36] = G[N,896] @ Wl + bl. Streaming, no LDS.
// ---------------------------------------------------------------------------
__global__ __launch_bounds__(256, 2) void gemm_final_kernel(
        const unsigned short* __restrict__ G, const short* __restrict__ WtF,
        const float* __restrict__ bl, float* __restrict__ out, int N) {
    const int tid = threadIdx.x;
    const int wave = tid >> 6;
    const int lane = tid & 63;
    const int quad = lane >> 4;
    const int l16 = lane & 15;
    const int m0 = blockIdx.x * 64;

    const int n0 = m0 + wave * 16 + l16;
    const long arow = (long)((n0 < N) ? n0 : (N - 1)) * 896;

    f32x4 acc[3];
#pragma unroll
    for (int ni = 0; ni < 3; ++ni) {
        int feat = ni * 16 + l16;
        float bv = (feat < 36) ? bl[feat] : 0.f;
        acc[ni][0] = bv; acc[ni][1] = bv; acc[ni][2] = bv; acc[ni][3] = bv;
    }

    const short* bp = WtF + (long)l16 * 896 + quad * 8;
#pragma unroll
    for (int ks = 0; ks < 28; ++ks) {
        f16x8 a = *(const f16x8*)&G[arow + ks * 32 + quad * 8];
        f16x8 b[3];
#pragma unroll
        for (int ni = 0; ni < 3; ++ni)
            b[ni] = *(const f16x8*)(bp + (long)ni * 16 * 896 + ks * 32);
#pragma unroll
        for (int ni = 0; ni < 3; ++ni)
            acc[ni] = __builtin_amdgcn_mfma_f32_16x16x32_f16(a, b[ni], acc[ni], 0, 0, 0);
    }

#pragma unroll
    for (int ni = 0; ni < 3; ++ni) {
        int feat = ni * 16 + l16;
        if (feat < 36) {
#pragma unroll
            for (int r = 0; r < 4; ++r) {
                int node = m0 + wave * 16 + quad * 4 + r;
                if (node < N) out[(long)node * 36 + feat] = acc[ni][r];
            }
        }
    }
}

// ---------------------------------------------------------------------------
extern "C" void kernel_launch(void* const* d_in, const int* in_sizes, int n_in,
                              void* d_out, int out_size, void* d_ws, size_t ws_size,
                              hipStream_t stream) {
    const float* x   = (const float*)d_in[0];
    const int*   idx = (const int*)d_in[1];
    const float* W0  = (const float*)d_in[2];
    const float* b0  = (const float*)d_in[3];
    const float* g0  = (const float*)d_in[4];
    const float* be0 = (const float*)d_in[5];
    const float* Wm  = (const float*)d_in[6];
    const float* bm  = (const float*)d_in[7];
    const float* gm  = (const float*)d_in[8];
    const float* bem = (const float*)d_in[9];
    const float* Wl  = (const float*)d_in[10];
    const float* bl  = (const float*)d_in[11];
    float* out = (float*)d_out;

    const int N = in_sizes[0] / 3;          // 40962
    const float invN = 1.0f / (float)N;

    char* ws = (char*)d_ws;
    size_t off = 0;
    auto alloc = [&](size_t bytes) -> void* {
        void* p = ws + off;
        off = (off + bytes + 255) & ~(size_t)255;
        return p;
    };
    short* WtM   = (short*)alloc(14UL * 128 * 896 * 2);
    short* WtF   = (short*)alloc(48UL * 896 * 2);
    float* stats = (float*)alloc(15UL * 256 * 4);
    unsigned short* hlin16 = (unsigned short*)alloc((size_t)N * 128 * 2);  // pre-BN h
    float* GX              = (float*)alloc((size_t)N * 21 * 4);            // gathered x
    unsigned short* G      = (unsigned short*)alloc((size_t)N * 896 * 2);  // gathered+BN

    {
        long total = 14L * 896 * 128 / 8 + 48L * 896 + 15L * 256;
        int blocks = (int)((total + 255) / 256);
        prep_kernel<<<blocks, 256, 0, stream>>>(Wm, Wl, WtM, WtF, stats);
    }

    const int gxtotal = N * 21;
    gx_kernel<<<(gxtotal + 255) / 256, 256, 0, stream>>>(x, idx, GX, gxtotal);
    l0_kernel<<<1024, 256, 0, stream>>>(GX, W0, b0, hlin16, stats, N);

    const int gtotal = N * 112;             // 16-B chunks of G
    const int gemmblocks = (N + 127) / 128; // 321

    bn_gather_kernel<<<2048, 256, 0, stream>>>(hlin16, stats, g0, be0, idx, G, gtotal, invN);

    for (int L = 0; L < 14; ++L) {
        gemm_g_kernel<<<gemmblocks, 256, 0, stream>>>(
            G, WtM + (size_t)L * 128 * 896, bm + L * 128,
            hlin16, stats + (L + 1) * 256, N);
        bn_gather_kernel<<<2048, 256, 0, stream>>>(
            hlin16, stats + (L + 1) * 256, gm + L * 128, bem + L * 128,
            idx, G, gtotal, invN);
    }

    gemm_final_kernel<<<(N + 63) / 64, 256, 0, stream>>>(G, WtF, bl, out, N);
}